// Round 7
// baseline (498.432 us; speedup 1.0000x reference)
//
#include <hip/hip_runtime.h>

typedef unsigned short u16;
typedef unsigned int u32;
typedef __attribute__((ext_vector_type(8))) short sh8;
typedef __attribute__((ext_vector_type(4))) float f32x4;
typedef __attribute__((ext_vector_type(4))) unsigned short us4;

__device__ __forceinline__ float bf2f(u16 u) {
  union { u32 i; float f; } x; x.i = ((u32)u) << 16; return x.f;
}
__device__ __forceinline__ u16 f2bf(float f) {
  union { float f; u32 i; } x; x.f = f;
  u32 u = x.i;
  u32 r = (u + 0x7FFFu + ((u >> 16) & 1u)) >> 16;
  return (u16)r;
}

// External tensors are float32 (confirmed R2/R3).
__device__ __forceinline__ sh8 load8f(const float* p, size_t off) {
  const float* f = p + off;
  f32x4 x = *(const f32x4*)f;
  f32x4 y = *(const f32x4*)(f + 4);
  sh8 r;
  r[0] = (short)f2bf(x[0]); r[1] = (short)f2bf(x[1]);
  r[2] = (short)f2bf(x[2]); r[3] = (short)f2bf(x[3]);
  r[4] = (short)f2bf(y[0]); r[5] = (short)f2bf(y[1]);
  r[6] = (short)f2bf(y[2]); r[7] = (short)f2bf(y[3]);
  return r;
}

// Physical col permutation: P(c) = (c&15)*8 + (c>>4); Lcol(p) = (p&7)*16 + (p>>3).

// ---------------- prep0: Wg-top f32 transpose + bias copies -----------------
__global__ void k_prep0(const float* __restrict__ Wg, const float* __restrict__ b_sage,
                        const float* __restrict__ bm, const float* __restrict__ ln_g,
                        const float* __restrict__ ln_b,
                        float* __restrict__ WgTtop, float* __restrict__ bm_f,
                        float* __restrict__ lng_f, float* __restrict__ lnb_f,
                        float* __restrict__ bsage_f) {
  int idx = blockIdx.x * blockDim.x + threadIdx.x;
  int stride = gridDim.x * blockDim.x;
  for (int i = idx; i < 16384; i += stride) {
    int c = i >> 7, j = i & 127;
    WgTtop[c * 128 + j] = Wg[j * 128 + c];
  }
  for (int i = idx; i < 128; i += stride) {
    bm_f[i] = bm[i];
    lng_f[i] = ln_g[i];
    lnb_f[i] = ln_b[i];
    bsage_f[i] = b_sage[i];
  }
}

// ---------------- prep1 + edge count (fused; independent work) --------------
__global__ void k_prep1c(const float* __restrict__ Ws, const float* __restrict__ Wn,
                         const float* __restrict__ Wm, const float* __restrict__ Wg,
                         u16* __restrict__ WmT, u16* __restrict__ WsT, u16* __restrict__ WnT,
                         u16* __restrict__ WgBT,
                         const int* __restrict__ dst, int* __restrict__ cnt, int E) {
  int idx = blockIdx.x * blockDim.x + threadIdx.x;
  int stride = gridDim.x * blockDim.x;
  for (int e = idx; e < E; e += stride) atomicAdd(&cnt[dst[e]], 1);
  for (int i = idx; i < 32768; i += stride) {
    int n = i >> 8, k = i & 255;
    WmT[n * 256 + k] = f2bf(Wm[k * 128 + n]);
  }
  for (int i = idx; i < 16384; i += stride) {
    int n = i >> 7, p = i & 127;
    WsT[i] = f2bf(Ws[p * 128 + n]);
    WnT[i] = f2bf(Wn[p * 128 + n]);
    int lc = (p & 7) * 16 + (p >> 3);  // K-dim pre-permuted for physical cagg
    WgBT[i] = f2bf(Wg[(128 + lc) * 128 + n]);
  }
}

// ---------------- prep2: fused gate weights -------------------------------
__global__ void k_prep2(const float* __restrict__ Ws, const float* __restrict__ Wn,
                        const float* __restrict__ WgTtop, const float* __restrict__ b_sage,
                        const float* __restrict__ bg,
                        u16* __restrict__ WsgT, u16* __restrict__ WngT,
                        float* __restrict__ bsg) {
  int i = blockIdx.x * blockDim.x + threadIdx.x;  // 16384 threads
  int c = i >> 7, k = i & 127;
  const float* wr = WgTtop + c * 128;
  const float* sr = Ws + k * 128;
  const float* nr = Wn + k * 128;
  float s1 = 0.f, s2 = 0.f;
#pragma unroll 8
  for (int j = 0; j < 128; j += 4) {
    f32x4 wg = *(const f32x4*)&wr[j];
    f32x4 a = *(const f32x4*)&sr[j];
    f32x4 b = *(const f32x4*)&nr[j];
    s1 += a[0] * wg[0] + a[1] * wg[1] + a[2] * wg[2] + a[3] * wg[3];
    s2 += b[0] * wg[0] + b[1] * wg[1] + b[2] * wg[2] + b[3] * wg[3];
  }
  WsgT[c * 128 + k] = f2bf(s1);
  WngT[c * 128 + k] = f2bf(s2);
  if (i < 128) {
    const float* wr2 = WgTtop + i * 128;
    float s = bg[i];
    for (int j = 0; j < 128; ++j) s += b_sage[j] * wr2[j];
    bsg[i] = s;
  }
}

// ---------------- parallel exclusive scan (3 phases) ------------------------
__global__ void k_scan1(const int* __restrict__ cnt, int* __restrict__ bsum, int N) {
  int i = blockIdx.x * 256 + threadIdx.x;
  int v = (i < N) ? cnt[i] : 0;
#pragma unroll
  for (int m = 1; m < 64; m <<= 1) v += __shfl_xor(v, m, 64);
  __shared__ int ws[4];
  if ((threadIdx.x & 63) == 0) ws[threadIdx.x >> 6] = v;
  __syncthreads();
  if (threadIdx.x == 0) bsum[blockIdx.x] = ws[0] + ws[1] + ws[2] + ws[3];
}

__global__ void k_scan2(const int* __restrict__ bsum, int* __restrict__ boff, int NB) {
  __shared__ int s[256];
  int t = threadIdx.x;
  int v = (t < NB) ? bsum[t] : 0;
  s[t] = v;
  __syncthreads();
  for (int off = 1; off < 256; off <<= 1) {
    int x = (t >= off) ? s[t - off] : 0;
    __syncthreads();
    s[t] += x;
    __syncthreads();
  }
  if (t < NB) boff[t] = s[t] - v;
}

__global__ void k_scan3(const int* __restrict__ cnt, const int* __restrict__ boff,
                        int* __restrict__ rowptr, int* __restrict__ cursor, int N) {
  __shared__ int s[256];
  int t = threadIdx.x;
  int i = blockIdx.x * 256 + t;
  int v = (i < N) ? cnt[i] : 0;
  s[t] = v;
  __syncthreads();
  for (int off = 1; off < 256; off <<= 1) {
    int x = (t >= off) ? s[t - off] : 0;
    __syncthreads();
    s[t] += x;
    __syncthreads();
  }
  int excl = boff[blockIdx.x] + s[t] - v;
  if (i < N) {
    rowptr[i] = excl;
    cursor[i] = excl;
    if (i == N - 1) rowptr[N] = excl + v;
  }
}

__global__ void k_perm(const int* __restrict__ src, const int* __restrict__ dst,
                       int* __restrict__ cursor, int* __restrict__ src_sorted, int E) {
  int e = blockIdx.x * blockDim.x + threadIdx.x;
  if (e < E) {
    int p = atomicAdd(&cursor[dst[e]], 1);
    src_sorted[p] = src[e];
  }
}

// ---------------- node kernel: M + per-node projections ---------------------
// hm[n][0..127] = bf16(h[n]) logical; hm[n][128..255] = M[n] physical (P).
// ab[n][0..127]  = (h@Ws + b_sage) physical; ab[n][128..255] = (h@Wsg + bsg) physical.
__global__ __launch_bounds__(512) void k_node(
    const float* __restrict__ h, const float* __restrict__ ctx,
    const u16* __restrict__ WmT, const u16* __restrict__ WsT, const u16* __restrict__ WsgT,
    const float* __restrict__ bm_f, const float* __restrict__ lng_f,
    const float* __restrict__ lnb_f, const float* __restrict__ bsage_f,
    const float* __restrict__ bsg,
    u16* __restrict__ hm, u16* __restrict__ ab, int N) {
  __shared__ u16 wlds[128 * 256];  // 64 KB: WmT, XOR-swizzled 16B chunks
  int tid = threadIdx.x;
  for (int it = 0; it < 8; ++it) {
    int f = tid + it * 512;
    int n = f >> 5;
    int kc = f & 31;
    int kcs = kc ^ (n & 7);
    *(sh8*)&wlds[n * 256 + kcs * 8] = *(const sh8*)&WmT[n * 256 + kc * 8];
  }
  __syncthreads();
  int lane = tid & 63;
  int wave = tid >> 6;
  int col = lane & 15;
  int quad = lane >> 4;
  float bmv[8], gv[8], bv[8], bsv[8], bgv[8];
#pragma unroll
  for (int t = 0; t < 8; ++t) {
    int c = t * 16 + col;
    bmv[t] = bm_f[c];
    gv[t] = lng_f[c];
    bv[t] = lnb_f[c];
    bsv[t] = bsage_f[c];
    bgv[t] = bsg[c];
  }
  int totalWaves = gridDim.x * 8;
  int TT = (N + 15) >> 4;
  for (int tile = blockIdx.x * 8 + wave; tile < TT; tile += totalWaves) {
    int n0 = tile * 16;
    int m = min(n0 + col, N - 1);
    f32x4 acc[8];
    sh8 afrag[4];
#pragma unroll
    for (int t = 0; t < 8; ++t) acc[t] = (f32x4)0.0f;
#pragma unroll
    for (int ks = 0; ks < 8; ++ks) {
      int k = ks * 32 + quad * 8;
      sh8 a = (k < 128) ? load8f(h, (size_t)m * 128 + k)
                        : load8f(ctx, (size_t)m * 128 + k - 128);
      if (ks < 4) afrag[ks & 3] = a;
#pragma unroll
      for (int t = 0; t < 8; ++t) {
        int n = t * 16 + col;
        int kc = ks * 4 + quad;
        int kcs = kc ^ (n & 7);
        sh8 b = *(const sh8*)&wlds[n * 256 + kcs * 8];
        acc[t] = __builtin_amdgcn_mfma_f32_16x16x32_bf16(a, b, acc[t], 0, 0, 0);
      }
    }
    // h-half store (logical order, 16B chunks)
#pragma unroll
    for (int ks = 0; ks < 4; ++ks)
      *(sh8*)&hm[(size_t)m * 256 + ks * 32 + quad * 8] = afrag[ks];
    // LayerNorm + ReLU; M-half store (physical order, 16B chunks)
#pragma unroll
    for (int r = 0; r < 4; ++r) {
      float v[8];
      float s1 = 0.f, s2 = 0.f;
#pragma unroll
      for (int t = 0; t < 8; ++t) {
        v[t] = acc[t][r] + bmv[t];
        s1 += v[t];
        s2 += v[t] * v[t];
      }
#pragma unroll
      for (int mm = 1; mm < 16; mm <<= 1) {
        s1 += __shfl_xor(s1, mm, 64);
        s2 += __shfl_xor(s2, mm, 64);
      }
      float mu = s1 * (1.f / 128.f);
      float var = s2 * (1.f / 128.f) - mu * mu;
      float rstd = rsqrtf(fmaxf(var, 0.f) + 1e-5f);
      int row = n0 + quad * 4 + r;
      if (row < N) {
        sh8 mv;
#pragma unroll
        for (int t = 0; t < 8; ++t) {
          float x = (v[t] - mu) * rstd * gv[t] + bv[t];
          x = x > 0.f ? x : 0.f;
          mv[t] = (short)f2bf(x);
        }
        *(sh8*)&hm[(size_t)row * 256 + 128 + col * 8] = mv;
      }
    }
    // GEMM2: ab1 = h@Ws + b_sage ; ab2 = h@Wsg + bsg  (B streamed from L2)
    f32x4 acc1[8], acc2[8];
#pragma unroll
    for (int t = 0; t < 8; ++t) {
      acc1[t] = (f32x4)0.0f;
      acc2[t] = (f32x4)0.0f;
    }
#pragma unroll
    for (int ks = 0; ks < 4; ++ks) {
#pragma unroll
      for (int t = 0; t < 8; ++t) {
        size_t bo = (size_t)(t * 16 + col) * 128 + ks * 32 + quad * 8;
        acc1[t] = __builtin_amdgcn_mfma_f32_16x16x32_bf16(afrag[ks], *(const sh8*)&WsT[bo],
                                                          acc1[t], 0, 0, 0);
        acc2[t] = __builtin_amdgcn_mfma_f32_16x16x32_bf16(afrag[ks], *(const sh8*)&WsgT[bo],
                                                          acc2[t], 0, 0, 0);
      }
    }
#pragma unroll
    for (int r = 0; r < 4; ++r) {
      int row = n0 + quad * 4 + r;
      if (row < N) {
        sh8 v1, v2;
#pragma unroll
        for (int t = 0; t < 8; ++t) {
          v1[t] = (short)f2bf(acc1[t][r] + bsv[t]);
          v2[t] = (short)f2bf(acc2[t][r] + bgv[t]);
        }
        *(sh8*)&ab[(size_t)row * 256 + col * 8] = v1;        // physical P
        *(sh8*)&ab[(size_t)row * 256 + 128 + col * 8] = v2;  // physical P
      }
    }
  }
}

// ---------------- fused aggregation + GEMM + gate + blend -------------------
// Block = 4 waves, 64 nodes. Phase 1: wave w gathers tile w (16 nodes) into a
// swizzled LDS A-tile [nm|cagg]. Phase 2: each wave takes a 32-col slice with
// B-frags in VGPRs and MFMAs all 4 tiles; epilogue blends and stores out.
__global__ __launch_bounds__(256) void k_aggout(
    const u16* __restrict__ hm, const int* __restrict__ rowptr,
    const int* __restrict__ src_sorted, const u16* __restrict__ ab,
    const u16* __restrict__ WnT, const u16* __restrict__ WngT,
    const u16* __restrict__ WgBT, float* __restrict__ out, int N) {
  __shared__ u16 atile[4 * 16 * 256];  // 32 KB
  int tid = threadIdx.x;
  int lane = tid & 63, wave = tid >> 6;
  int tile = blockIdx.x * 4 + wave;
  // ---- phase 1: gather ----
  {
    int chunk = lane >> 1;        // 16B chunk index 0..31 within a 512B row
    int halfu = (lane & 1) * 4;   // u16 offset within chunk
    for (int i = 0; i < 16; ++i) {
      int n = tile * 16 + i;
      float s0 = 0.f, s1 = 0.f, s2 = 0.f, s3 = 0.f;
      int b = 0, e = 0;
      if (n < N) { b = rowptr[n]; e = rowptr[n + 1]; }
      int j = b;
      for (; j + 4 <= e; j += 4) {
        int e0 = src_sorted[j], e1 = src_sorted[j + 1];
        int e2 = src_sorted[j + 2], e3 = src_sorted[j + 3];
        us4 v0 = *(const us4*)(hm + (size_t)e0 * 256 + (lane << 2));
        us4 v1 = *(const us4*)(hm + (size_t)e1 * 256 + (lane << 2));
        us4 v2 = *(const us4*)(hm + (size_t)e2 * 256 + (lane << 2));
        us4 v3 = *(const us4*)(hm + (size_t)e3 * 256 + (lane << 2));
        s0 += bf2f(v0[0]) + bf2f(v1[0]) + bf2f(v2[0]) + bf2f(v3[0]);
        s1 += bf2f(v0[1]) + bf2f(v1[1]) + bf2f(v2[1]) + bf2f(v3[1]);
        s2 += bf2f(v0[2]) + bf2f(v1[2]) + bf2f(v2[2]) + bf2f(v3[2]);
        s3 += bf2f(v0[3]) + bf2f(v1[3]) + bf2f(v2[3]) + bf2f(v3[3]);
      }
      for (; j < e; ++j) {
        int e0 = src_sorted[j];
        us4 v0 = *(const us4*)(hm + (size_t)e0 * 256 + (lane << 2));
        s0 += bf2f(v0[0]);
        s1 += bf2f(v0[1]);
        s2 += bf2f(v0[2]);
        s3 += bf2f(v0[3]);
      }
      float inv = (e > b) ? 1.f / (float)(e - b) : 0.f;
      us4 p;
      p[0] = f2bf(s0 * inv); p[1] = f2bf(s1 * inv);
      p[2] = f2bf(s2 * inv); p[3] = f2bf(s3 * inv);
      *(us4*)&atile[wave * 4096 + i * 256 + ((chunk ^ (i & 7)) << 3) + halfu] = p;
    }
  }
  __syncthreads();
  // ---- phase 2: MFMA over all 4 tiles, this wave's 32-col slice ----
  int col16 = lane & 15, quad = lane >> 4;
  sh8 bn[4][2], bq[4][2], bb[4][2];
#pragma unroll
  for (int ks = 0; ks < 4; ++ks) {
#pragma unroll
    for (int t = 0; t < 2; ++t) {
      size_t bo = (size_t)(wave * 32 + t * 16 + col16) * 128 + ks * 32 + quad * 8;
      bn[ks][t] = *(const sh8*)&WnT[bo];
      bq[ks][t] = *(const sh8*)&WngT[bo];
      bb[ks][t] = *(const sh8*)&WgBT[bo];
    }
  }
#pragma unroll
  for (int t4 = 0; t4 < 4; ++t4) {
    int tb = blockIdx.x * 4 + t4;
    sh8 an[4], ac[4];
#pragma unroll
    for (int ks = 0; ks < 4; ++ks) {
      int kc1 = ks * 4 + quad;
      int kc2 = 16 + ks * 4 + quad;
      an[ks] = *(const sh8*)&atile[t4 * 4096 + col16 * 256 + ((kc1 ^ (col16 & 7)) << 3)];
      ac[ks] = *(const sh8*)&atile[t4 * 4096 + col16 * 256 + ((kc2 ^ (col16 & 7)) << 3)];
    }
    f32x4 as_[2], ag[2];
#pragma unroll
    for (int t = 0; t < 2; ++t) {
      as_[t] = (f32x4)0.0f;
      ag[t] = (f32x4)0.0f;
    }
#pragma unroll
    for (int ks = 0; ks < 4; ++ks) {
#pragma unroll
      for (int t = 0; t < 2; ++t) {
        as_[t] = __builtin_amdgcn_mfma_f32_16x16x32_bf16(an[ks], bn[ks][t], as_[t], 0, 0, 0);
        ag[t] = __builtin_amdgcn_mfma_f32_16x16x32_bf16(an[ks], bq[ks][t], ag[t], 0, 0, 0);
        ag[t] = __builtin_amdgcn_mfma_f32_16x16x32_bf16(ac[ks], bb[ks][t], ag[t], 0, 0, 0);
      }
    }
#pragma unroll
    for (int r = 0; r < 4; ++r) {
      int n = tb * 16 + quad * 4 + r;
      if (n < N) {
#pragma unroll
        for (int t = 0; t < 2; ++t) {
          int gc = wave * 32 + t * 16 + col16;
          float a1 = bf2f(ab[(size_t)n * 256 + col16 * 8 + wave * 2 + t]);
          float a2 = bf2f(ab[(size_t)n * 256 + 128 + col16 * 8 + wave * 2 + t]);
          float sv = as_[t][r] + a1;
          float gl = ag[t][r] + a2;
          float g = 1.f / (1.f + __expf(-gl));
          // cagg (raw M mean) from LDS; physical pc = col16*8 + wave*2 + t
          int mrow = quad * 4 + r;
          int pc = col16 * 8 + wave * 2 + t;
          int uoff = 128 + pc;          // u16 offset within row
          int kc = uoff >> 3;           // 16B chunk
          int within = uoff & 7;
          u16 cv = atile[t4 * 4096 + mrow * 256 + ((kc ^ (mrow & 7)) << 3) + within];
          float ca = bf2f(cv);
          out[(size_t)n * 128 + gc] = g * sv + (1.f - g) * ca;
        }
      }
    }
  }
}

extern "C" void kernel_launch(void* const* d_in, const int* in_sizes, int n_in,
                              void* d_out, int out_size, void* d_ws, size_t ws_size,
                              hipStream_t stream) {
  const float* h = (const float*)d_in[0];
  const float* ctx = (const float*)d_in[1];
  const int* src = (const int*)d_in[2];
  const int* dst = (const int*)d_in[3];
  const float* Ws = (const float*)d_in[4];
  const float* Wn = (const float*)d_in[5];
  const float* b_sage = (const float*)d_in[6];
  const float* Wm = (const float*)d_in[7];
  const float* bm = (const float*)d_in[8];
  const float* ln_g = (const float*)d_in[9];
  const float* ln_b = (const float*)d_in[10];
  const float* Wg = (const float*)d_in[11];
  const float* bg = (const float*)d_in[12];
  int N = in_sizes[0] / 128;
  int E = in_sizes[2];

  char* w = (char*)d_ws;
  auto carve = [&](size_t bytes) {
    char* p = w;
    w += (bytes + 255) & ~(size_t)255;
    return p;
  };
  int* cnt = (int*)carve((size_t)N * 4);
  int* rowptr = (int*)carve((size_t)(N + 1) * 4);
  int* cursor = (int*)carve((size_t)N * 4);
  int* src_sorted = (int*)carve((size_t)E * 4);
  int NB = (N + 255) / 256;
  int* bsum = (int*)carve((size_t)NB * 4);
  int* boff = (int*)carve((size_t)NB * 4);
  float* WgTtop = (float*)carve(16384 * 4);
  u16* WmT = (u16*)carve(32768 * 2);
  u16* WsT = (u16*)carve(16384 * 2);
  u16* WnT = (u16*)carve(16384 * 2);
  u16* WsgT = (u16*)carve(16384 * 2);
  u16* WngT = (u16*)carve(16384 * 2);
  u16* WgBT = (u16*)carve(16384 * 2);
  float* bm_f = (float*)carve(128 * 4);
  float* lng_f = (float*)carve(128 * 4);
  float* lnb_f = (float*)carve(128 * 4);
  float* bsage_f = (float*)carve(128 * 4);
  float* bsg = (float*)carve(128 * 4);
  u16* hm = (u16*)carve((size_t)N * 256 * 2);
  u16* ab = (u16*)carve((size_t)N * 256 * 2);

  hipMemsetAsync(cnt, 0, (size_t)N * 4, stream);
  k_prep0<<<64, 256, 0, stream>>>(Wg, b_sage, bm, ln_g, ln_b, WgTtop, bm_f, lng_f,
                                  lnb_f, bsage_f);
  k_prep1c<<<(E + 255) / 256, 256, 0, stream>>>(Ws, Wn, Wm, Wg, WmT, WsT, WnT, WgBT,
                                                dst, cnt, E);
  k_prep2<<<64, 256, 0, stream>>>(Ws, Wn, WgTtop, b_sage, bg, WsgT, WngT, bsg);
  k_scan1<<<NB, 256, 0, stream>>>(cnt, bsum, N);
  k_scan2<<<1, 256, 0, stream>>>(bsum, boff, NB);
  k_scan3<<<NB, 256, 0, stream>>>(cnt, boff, rowptr, cursor, N);
  k_perm<<<(E + 255) / 256, 256, 0, stream>>>(src, dst, cursor, src_sorted, E);
  int TT = (N + 15) / 16;
  int nb = (TT + 7) / 8;
  k_node<<<nb, 512, 0, stream>>>(h, ctx, WmT, WsT, WsgT, bm_f, lng_f, lnb_f, bsage_f,
                                 bsg, hm, ab, N);
  int nblk = (TT + 3) / 4;
  k_aggout<<<nblk, 256, 0, stream>>>(hm, rowptr, src_sorted, ab, WnT, WngT, WgBT,
                                     (float*)d_out, N);
}

// Round 8
// 314.714 us; speedup vs baseline: 1.5838x; 1.5838x over previous
//
#include <hip/hip_runtime.h>

typedef unsigned short u16;
typedef unsigned int u32;
typedef __attribute__((ext_vector_type(8))) short sh8;
typedef __attribute__((ext_vector_type(4))) float f32x4;

__device__ __forceinline__ float bf2f(u16 u) {
  union { u32 i; float f; } x; x.i = ((u32)u) << 16; return x.f;
}
__device__ __forceinline__ u16 f2bf(float f) {
  union { float f; u32 i; } x; x.f = f;
  u32 u = x.i;
  u32 r = (u + 0x7FFFu + ((u >> 16) & 1u)) >> 16;
  return (u16)r;
}

// External tensors are float32 (confirmed R2/R3).
__device__ __forceinline__ sh8 load8f(const float* p, size_t off) {
  const float* f = p + off;
  f32x4 x = *(const f32x4*)f;
  f32x4 y = *(const f32x4*)(f + 4);
  sh8 r;
  r[0] = (short)f2bf(x[0]); r[1] = (short)f2bf(x[1]);
  r[2] = (short)f2bf(x[2]); r[3] = (short)f2bf(x[3]);
  r[4] = (short)f2bf(y[0]); r[5] = (short)f2bf(y[1]);
  r[6] = (short)f2bf(y[2]); r[7] = (short)f2bf(y[3]);
  return r;
}

// Physical col permutation: P(c) = (c&15)*8 + (c>>4); Lcol(p) = (p&7)*16 + (p>>3).

// ---------------- prep0: Wg-top f32 transpose + bias copies -----------------
__global__ void k_prep0(const float* __restrict__ Wg, const float* __restrict__ b_sage,
                        const float* __restrict__ bm, const float* __restrict__ ln_g,
                        const float* __restrict__ ln_b,
                        float* __restrict__ WgTtop, float* __restrict__ bm_f,
                        float* __restrict__ lng_f, float* __restrict__ lnb_f,
                        float* __restrict__ bsage_f) {
  int idx = blockIdx.x * blockDim.x + threadIdx.x;
  int stride = gridDim.x * blockDim.x;
  for (int i = idx; i < 16384; i += stride) {
    int c = i >> 7, j = i & 127;
    WgTtop[c * 128 + j] = Wg[j * 128 + c];
  }
  for (int i = idx; i < 128; i += stride) {
    bm_f[i] = bm[i];
    lng_f[i] = ln_g[i];
    lnb_f[i] = ln_b[i];
    bsage_f[i] = b_sage[i];
  }
}

// ---------------- prep1 + edge count (fused; independent work) --------------
__global__ void k_prep1c(const float* __restrict__ Ws, const float* __restrict__ Wn,
                         const float* __restrict__ Wm, const float* __restrict__ Wg,
                         u16* __restrict__ WmT, u16* __restrict__ WsT, u16* __restrict__ WnT,
                         u16* __restrict__ WgBT,
                         const int* __restrict__ dst, int* __restrict__ cnt, int E) {
  int idx = blockIdx.x * blockDim.x + threadIdx.x;
  int stride = gridDim.x * blockDim.x;
  for (int e = idx; e < E; e += stride) atomicAdd(&cnt[dst[e]], 1);
  for (int i = idx; i < 32768; i += stride) {
    int n = i >> 8, k = i & 255;
    WmT[n * 256 + k] = f2bf(Wm[k * 128 + n]);
  }
  for (int i = idx; i < 16384; i += stride) {
    int n = i >> 7, p = i & 127;
    WsT[i] = f2bf(Ws[p * 128 + n]);
    WnT[i] = f2bf(Wn[p * 128 + n]);
    int lc = (p & 7) * 16 + (p >> 3);  // K-dim pre-permuted for physical cagg
    WgBT[i] = f2bf(Wg[(128 + lc) * 128 + n]);
  }
}

// ---------------- prep2: fused gate weights -------------------------------
__global__ void k_prep2(const float* __restrict__ Ws, const float* __restrict__ Wn,
                        const float* __restrict__ WgTtop, const float* __restrict__ b_sage,
                        const float* __restrict__ bg,
                        u16* __restrict__ WsgT, u16* __restrict__ WngT,
                        float* __restrict__ bsg) {
  int i = blockIdx.x * blockDim.x + threadIdx.x;  // 16384 threads
  int c = i >> 7, k = i & 127;
  const float* wr = WgTtop + c * 128;
  const float* sr = Ws + k * 128;
  const float* nr = Wn + k * 128;
  float s1 = 0.f, s2 = 0.f;
#pragma unroll 8
  for (int j = 0; j < 128; j += 4) {
    f32x4 wg = *(const f32x4*)&wr[j];
    f32x4 a = *(const f32x4*)&sr[j];
    f32x4 b = *(const f32x4*)&nr[j];
    s1 += a[0] * wg[0] + a[1] * wg[1] + a[2] * wg[2] + a[3] * wg[3];
    s2 += b[0] * wg[0] + b[1] * wg[1] + b[2] * wg[2] + b[3] * wg[3];
  }
  WsgT[c * 128 + k] = f2bf(s1);
  WngT[c * 128 + k] = f2bf(s2);
  if (i < 128) {
    const float* wr2 = WgTtop + i * 128;
    float s = bg[i];
    for (int j = 0; j < 128; ++j) s += b_sage[j] * wr2[j];
    bsg[i] = s;
  }
}

// ---------------- parallel exclusive scan (3 phases) ------------------------
__global__ void k_scan1(const int* __restrict__ cnt, int* __restrict__ bsum, int N) {
  int i = blockIdx.x * 256 + threadIdx.x;
  int v = (i < N) ? cnt[i] : 0;
#pragma unroll
  for (int m = 1; m < 64; m <<= 1) v += __shfl_xor(v, m, 64);
  __shared__ int ws[4];
  if ((threadIdx.x & 63) == 0) ws[threadIdx.x >> 6] = v;
  __syncthreads();
  if (threadIdx.x == 0) bsum[blockIdx.x] = ws[0] + ws[1] + ws[2] + ws[3];
}

__global__ void k_scan2(const int* __restrict__ bsum, int* __restrict__ boff, int NB) {
  __shared__ int s[256];
  int t = threadIdx.x;
  int v = (t < NB) ? bsum[t] : 0;
  s[t] = v;
  __syncthreads();
  for (int off = 1; off < 256; off <<= 1) {
    int x = (t >= off) ? s[t - off] : 0;
    __syncthreads();
    s[t] += x;
    __syncthreads();
  }
  if (t < NB) boff[t] = s[t] - v;
}

__global__ void k_scan3(const int* __restrict__ cnt, const int* __restrict__ boff,
                        int* __restrict__ rowptr, int* __restrict__ cursor, int N) {
  __shared__ int s[256];
  int t = threadIdx.x;
  int i = blockIdx.x * 256 + t;
  int v = (i < N) ? cnt[i] : 0;
  s[t] = v;
  __syncthreads();
  for (int off = 1; off < 256; off <<= 1) {
    int x = (t >= off) ? s[t - off] : 0;
    __syncthreads();
    s[t] += x;
    __syncthreads();
  }
  int excl = boff[blockIdx.x] + s[t] - v;
  if (i < N) {
    rowptr[i] = excl;
    cursor[i] = excl;
    if (i == N - 1) rowptr[N] = excl + v;
  }
}

__global__ void k_perm(const int* __restrict__ src, const int* __restrict__ dst,
                       int* __restrict__ cursor, int* __restrict__ src_sorted, int E) {
  int e = blockIdx.x * blockDim.x + threadIdx.x;
  if (e < E) {
    int p = atomicAdd(&cursor[dst[e]], 1);
    src_sorted[p] = src[e];
  }
}

// ---------------- node MLP: M = relu(LN(concat(h,ctx)@Wm + bm)) -------------
// hm[n][0..127] = bf16(h[n]) logical; hm[n][128..255] = M[n] physical (P).
__global__ __launch_bounds__(512) void k_node(
    const float* __restrict__ h, const float* __restrict__ ctx,
    const u16* __restrict__ WmT, const float* __restrict__ bm_f,
    const float* __restrict__ lng_f, const float* __restrict__ lnb_f,
    u16* __restrict__ hm, int N) {
  __shared__ u16 wlds[128 * 256];  // 64 KB: WmT, XOR-swizzled 16B chunks
  int tid = threadIdx.x;
  for (int it = 0; it < 8; ++it) {
    int f = tid + it * 512;
    int n = f >> 5;
    int kc = f & 31;
    int kcs = kc ^ (n & 7);
    *(sh8*)&wlds[n * 256 + kcs * 8] = *(const sh8*)&WmT[n * 256 + kc * 8];
  }
  __syncthreads();
  int lane = tid & 63;
  int wave = tid >> 6;
  int col = lane & 15;
  int quad = lane >> 4;
  float bmv[8], gv[8], bv[8];
#pragma unroll
  for (int t = 0; t < 8; ++t) {
    int c = t * 16 + col;
    bmv[t] = bm_f[c];
    gv[t] = lng_f[c];
    bv[t] = lnb_f[c];
  }
  int totalWaves = gridDim.x * 8;
  int TT = (N + 15) >> 4;
  for (int tile = blockIdx.x * 8 + wave; tile < TT; tile += totalWaves) {
    int n0 = tile * 16;
    int m = min(n0 + col, N - 1);
    f32x4 acc[8];
    sh8 afrag[4];
#pragma unroll
    for (int t = 0; t < 8; ++t) acc[t] = (f32x4)0.0f;
#pragma unroll
    for (int ks = 0; ks < 8; ++ks) {
      int k = ks * 32 + quad * 8;
      sh8 a = (k < 128) ? load8f(h, (size_t)m * 128 + k)
                        : load8f(ctx, (size_t)m * 128 + k - 128);
      if (ks < 4) afrag[ks & 3] = a;
#pragma unroll
      for (int t = 0; t < 8; ++t) {
        int n = t * 16 + col;
        int kc = ks * 4 + quad;
        int kcs = kc ^ (n & 7);
        sh8 b = *(const sh8*)&wlds[n * 256 + kcs * 8];
        acc[t] = __builtin_amdgcn_mfma_f32_16x16x32_bf16(a, b, acc[t], 0, 0, 0);
      }
    }
#pragma unroll
    for (int ks = 0; ks < 4; ++ks)
      *(sh8*)&hm[(size_t)m * 256 + ks * 32 + quad * 8] = afrag[ks];
#pragma unroll
    for (int r = 0; r < 4; ++r) {
      float v[8];
      float s1 = 0.f, s2 = 0.f;
#pragma unroll
      for (int t = 0; t < 8; ++t) {
        v[t] = acc[t][r] + bmv[t];
        s1 += v[t];
        s2 += v[t] * v[t];
      }
#pragma unroll
      for (int mm = 1; mm < 16; mm <<= 1) {
        s1 += __shfl_xor(s1, mm, 64);
        s2 += __shfl_xor(s2, mm, 64);
      }
      float mu = s1 * (1.f / 128.f);
      float var = s2 * (1.f / 128.f) - mu * mu;
      float rstd = rsqrtf(fmaxf(var, 0.f) + 1e-5f);
      int row = n0 + quad * 4 + r;
      if (row < N) {
        sh8 mv;
#pragma unroll
        for (int t = 0; t < 8; ++t) {
          float x = (v[t] - mu) * rstd * gv[t] + bv[t];
          x = x > 0.f ? x : 0.f;
          mv[t] = (short)f2bf(x);
        }
        *(sh8*)&hm[(size_t)row * 256 + 128 + col * 8] = mv;
      }
    }
  }
}

// ---------------- per-node aggregation over hm rows -------------------------
// 16B/lane: lanes 0-31 cover edge j, lanes 32-63 edge j+1 -> 2 edges per
// wave-load, 8 edges in flight at unroll 4 (2x R6's MLP, half the instrs).
__global__ __launch_bounds__(256) void k_agg(
    const u16* __restrict__ hm, const int* __restrict__ rowptr,
    const int* __restrict__ src_sorted,
    u16* __restrict__ nm, u16* __restrict__ cagg, int N) {
  int gw = (blockIdx.x * 256 + threadIdx.x) >> 6;
  int lane = threadIdx.x & 63;
  int tw = (gridDim.x * 256) >> 6;
  int pair = lane >> 5;   // which edge of a pair
  int sub = lane & 31;    // 16B chunk within the 512B row
  for (int n = gw; n < N; n += tw) {
    int b = rowptr[n], e = rowptr[n + 1];
    float s[8];
#pragma unroll
    for (int c = 0; c < 8; ++c) s[c] = 0.f;
    int j = b;
    for (; j + 8 <= e; j += 8) {
      int e0 = src_sorted[j + pair];
      int e1 = src_sorted[j + 2 + pair];
      int e2 = src_sorted[j + 4 + pair];
      int e3 = src_sorted[j + 6 + pair];
      sh8 v0 = *(const sh8*)(hm + (size_t)e0 * 256 + sub * 8);
      sh8 v1 = *(const sh8*)(hm + (size_t)e1 * 256 + sub * 8);
      sh8 v2 = *(const sh8*)(hm + (size_t)e2 * 256 + sub * 8);
      sh8 v3 = *(const sh8*)(hm + (size_t)e3 * 256 + sub * 8);
#pragma unroll
      for (int c = 0; c < 8; ++c)
        s[c] += bf2f((u16)v0[c]) + bf2f((u16)v1[c]) + bf2f((u16)v2[c]) + bf2f((u16)v3[c]);
    }
    for (; j + 2 <= e; j += 2) {
      int e0 = src_sorted[j + pair];
      sh8 v0 = *(const sh8*)(hm + (size_t)e0 * 256 + sub * 8);
#pragma unroll
      for (int c = 0; c < 8; ++c) s[c] += bf2f((u16)v0[c]);
    }
    if (j < e && pair == 0) {  // odd leftover edge: half-wave only
      int e0 = src_sorted[j];
      sh8 v0 = *(const sh8*)(hm + (size_t)e0 * 256 + sub * 8);
#pragma unroll
      for (int c = 0; c < 8; ++c) s[c] += bf2f((u16)v0[c]);
    }
#pragma unroll
    for (int c = 0; c < 8; ++c) s[c] += __shfl_xor(s[c], 32, 64);
    float inv = (e > b) ? 1.f / (float)(e - b) : 0.f;
    if (lane < 32) {
      sh8 p;
#pragma unroll
      for (int c = 0; c < 8; ++c) p[c] = (short)f2bf(s[c] * inv);
      if (sub < 16)
        *(sh8*)&nm[(size_t)n * 128 + sub * 8] = p;           // h-mean, logical
      else
        *(sh8*)&cagg[(size_t)n * 128 + (sub - 16) * 8] = p;  // M-mean, physical
    }
  }
}

// ---------------- fused node GEMMs + gate + blend (col-split, LDS-B) --------
__global__ __launch_bounds__(256) void k_out(
    const u16* __restrict__ hm, const u16* __restrict__ nm, const u16* __restrict__ cagg,
    const u16* __restrict__ WsT, const u16* __restrict__ WnT,
    const u16* __restrict__ WsgT, const u16* __restrict__ WngT, const u16* __restrict__ WgBT,
    const float* __restrict__ bsage_f, const float* __restrict__ bsg,
    float* __restrict__ out, int N) {
  __shared__ u16 blds[5 * 32 * 128];  // 40 KB
  int tid = threadIdx.x;
  int q = blockIdx.x & 3;  // column group: global cols q*32 .. q*32+31
  {
    const u16* matp[5] = {WsT, WnT, WsgT, WngT, WgBT};
#pragma unroll
    for (int m = 0; m < 5; ++m) {
#pragma unroll
      for (int j = 0; j < 2; ++j) {
        int f = tid + j * 256;
        int lc = f >> 4, kc = f & 15;
        int kcs = kc ^ (lc & 15);
        *(sh8*)&blds[(m * 32 + lc) * 128 + kcs * 8] =
            *(const sh8*)&matp[m][(size_t)(q * 32 + lc) * 128 + kc * 8];
      }
    }
  }
  __syncthreads();
  int lane = tid & 63;
  int wave = tid >> 6;
  int col = lane & 15, quad = lane >> 4;
  float bsv[2], bgv[2];
#pragma unroll
  for (int tt = 0; tt < 2; ++tt) {
    int gc = q * 32 + tt * 16 + col;
    bsv[tt] = bsage_f[gc];
    bgv[tt] = bsg[gc];
  }
  int TT = (N + 15) >> 4;
  int stride = gridDim.x;
  for (int tile = (blockIdx.x >> 2) * 4 + wave; tile < TT; tile += stride) {
    int nr = min(tile * 16 + col, N - 1);
    sh8 ah[4], am[4], ac[4];
#pragma unroll
    for (int ks = 0; ks < 4; ++ks) {
      int k = ks * 32 + quad * 8;
      ah[ks] = *(const sh8*)&hm[(size_t)nr * 256 + k];
      am[ks] = *(const sh8*)&nm[(size_t)nr * 128 + k];
      ac[ks] = *(const sh8*)&cagg[(size_t)nr * 128 + k];  // physical k, WgBT matches
    }
    f32x4 as[2], ag[2];
#pragma unroll
    for (int tt = 0; tt < 2; ++tt) {
      as[tt] = (f32x4)0.0f;
      ag[tt] = (f32x4)0.0f;
    }
#pragma unroll
    for (int ks = 0; ks < 4; ++ks) {
      int kc = ks * 4 + quad;
      int kcs8 = (kc ^ col) * 8;
#pragma unroll
      for (int tt = 0; tt < 2; ++tt) {
        int lc = tt * 16 + col;
        sh8 b1 = *(const sh8*)&blds[(0 * 32 + lc) * 128 + kcs8];
        sh8 b2 = *(const sh8*)&blds[(1 * 32 + lc) * 128 + kcs8];
        sh8 b3 = *(const sh8*)&blds[(2 * 32 + lc) * 128 + kcs8];
        sh8 b4 = *(const sh8*)&blds[(3 * 32 + lc) * 128 + kcs8];
        sh8 b5 = *(const sh8*)&blds[(4 * 32 + lc) * 128 + kcs8];
        as[tt] = __builtin_amdgcn_mfma_f32_16x16x32_bf16(ah[ks], b1, as[tt], 0, 0, 0);
        as[tt] = __builtin_amdgcn_mfma_f32_16x16x32_bf16(am[ks], b2, as[tt], 0, 0, 0);
        ag[tt] = __builtin_amdgcn_mfma_f32_16x16x32_bf16(ah[ks], b3, ag[tt], 0, 0, 0);
        ag[tt] = __builtin_amdgcn_mfma_f32_16x16x32_bf16(am[ks], b4, ag[tt], 0, 0, 0);
        ag[tt] = __builtin_amdgcn_mfma_f32_16x16x32_bf16(ac[ks], b5, ag[tt], 0, 0, 0);
      }
    }
#pragma unroll
    for (int r = 0; r < 4; ++r) {
      int n = tile * 16 + quad * 4 + r;
      if (n < N) {
#pragma unroll
        for (int tt = 0; tt < 2; ++tt) {
          int gc = q * 32 + tt * 16 + col;
          float sv = as[tt][r] + bsv[tt];
          float gl = ag[tt][r] + bgv[tt];
          float g = 1.f / (1.f + __expf(-gl));
          int pc = (gc & 15) * 8 + (gc >> 4);  // P(gc): physical position
          float ca = bf2f(cagg[(size_t)n * 128 + pc]);
          out[(size_t)n * 128 + gc] = g * sv + (1.f - g) * ca;
        }
      }
    }
  }
}

extern "C" void kernel_launch(void* const* d_in, const int* in_sizes, int n_in,
                              void* d_out, int out_size, void* d_ws, size_t ws_size,
                              hipStream_t stream) {
  const float* h = (const float*)d_in[0];
  const float* ctx = (const float*)d_in[1];
  const int* src = (const int*)d_in[2];
  const int* dst = (const int*)d_in[3];
  const float* Ws = (const float*)d_in[4];
  const float* Wn = (const float*)d_in[5];
  const float* b_sage = (const float*)d_in[6];
  const float* Wm = (const float*)d_in[7];
  const float* bm = (const float*)d_in[8];
  const float* ln_g = (const float*)d_in[9];
  const float* ln_b = (const float*)d_in[10];
  const float* Wg = (const float*)d_in[11];
  const float* bg = (const float*)d_in[12];
  int N = in_sizes[0] / 128;
  int E = in_sizes[2];

  char* w = (char*)d_ws;
  auto carve = [&](size_t bytes) {
    char* p = w;
    w += (bytes + 255) & ~(size_t)255;
    return p;
  };
  int* cnt = (int*)carve((size_t)N * 4);
  int* rowptr = (int*)carve((size_t)(N + 1) * 4);
  int* cursor = (int*)carve((size_t)N * 4);
  int* src_sorted = (int*)carve((size_t)E * 4);
  int NB = (N + 255) / 256;
  int* bsum = (int*)carve((size_t)NB * 4);
  int* boff = (int*)carve((size_t)NB * 4);
  float* WgTtop = (float*)carve(16384 * 4);
  u16* WmT = (u16*)carve(32768 * 2);
  u16* WsT = (u16*)carve(16384 * 2);
  u16* WnT = (u16*)carve(16384 * 2);
  u16* WsgT = (u16*)carve(16384 * 2);
  u16* WngT = (u16*)carve(16384 * 2);
  u16* WgBT = (u16*)carve(16384 * 2);
  float* bm_f = (float*)carve(128 * 4);
  float* lng_f = (float*)carve(128 * 4);
  float* lnb_f = (float*)carve(128 * 4);
  float* bsage_f = (float*)carve(128 * 4);
  float* bsg = (float*)carve(128 * 4);
  u16* hm = (u16*)carve((size_t)N * 256 * 2);
  u16* nm = (u16*)carve((size_t)N * 128 * 2);
  u16* cagg = (u16*)carve((size_t)N * 128 * 2);

  hipMemsetAsync(cnt, 0, (size_t)N * 4, stream);
  k_prep0<<<64, 256, 0, stream>>>(Wg, b_sage, bm, ln_g, ln_b, WgTtop, bm_f, lng_f,
                                  lnb_f, bsage_f);
  k_prep1c<<<(E + 255) / 256, 256, 0, stream>>>(Ws, Wn, Wm, Wg, WmT, WsT, WnT, WgBT,
                                                dst, cnt, E);
  k_prep2<<<64, 256, 0, stream>>>(Ws, Wn, WgTtop, b_sage, bg, WsgT, WngT, bsg);
  k_scan1<<<NB, 256, 0, stream>>>(cnt, bsum, N);
  k_scan2<<<1, 256, 0, stream>>>(bsum, boff, NB);
  k_scan3<<<NB, 256, 0, stream>>>(cnt, boff, rowptr, cursor, N);
  k_perm<<<(E + 255) / 256, 256, 0, stream>>>(src, dst, cursor, src_sorted, E);
  int TT = (N + 15) / 16;
  int nb = (TT + 7) / 8;
  k_node<<<nb, 512, 0, stream>>>(h, ctx, WmT, bm_f, lng_f, lnb_f, hm, N);
  k_agg<<<2048, 256, 0, stream>>>(hm, rowptr, src_sorted, nm, cagg, N);
  k_out<<<1024, 256, 0, stream>>>(hm, nm, cagg, WsT, WnT, WsgT, WngT, WgBT,
                                  bsage_f, bsg, (float*)d_out, N);
}